// Round 2
// baseline (1994.872 us; speedup 1.0000x reference)
//
#include <hip/hip_runtime.h>

#define NN 30000   // nodes
#define MMN 16     // neighbors
#define NF 1024    // input features
#define NC 16      // classes
#define KC 8       // capsules
#define DDIM 32    // dims per capsule
#define DR 256     // rep dim

// ---------------- PCA GEMM: P = relu(x @ w + b) ----------------
// x [NN,NF], w [NF,DR], b [DR]. Block 256 = 4 waves; wave: 8 rows, lane: 4 cols.
__global__ __launch_bounds__(256) void pca_kernel(
    const float* __restrict__ x, const float* __restrict__ w,
    const float* __restrict__ b, float* __restrict__ out) {
  const int lane = threadIdx.x & 63;
  const int wid  = threadIdx.x >> 6;
  const int r0   = blockIdx.x * 32 + wid * 8;
  if (r0 >= NN) return;
  const int c = lane * 4;
  float4 acc[8];
  const float4 bb = *(const float4*)(b + c);
#pragma unroll
  for (int r = 0; r < 8; ++r) acc[r] = bb;
  for (int k = 0; k < NF; k += 4) {
    const float4 w0 = *(const float4*)(w + (size_t)(k+0)*DR + c);
    const float4 w1 = *(const float4*)(w + (size_t)(k+1)*DR + c);
    const float4 w2 = *(const float4*)(w + (size_t)(k+2)*DR + c);
    const float4 w3 = *(const float4*)(w + (size_t)(k+3)*DR + c);
#pragma unroll
    for (int r = 0; r < 8; ++r) {
      const float4 xv = *(const float4*)(x + (size_t)(r0+r)*NF + k);
      acc[r].x += xv.x*w0.x + xv.y*w1.x + xv.z*w2.x + xv.w*w3.x;
      acc[r].y += xv.x*w0.y + xv.y*w1.y + xv.z*w2.y + xv.w*w3.y;
      acc[r].z += xv.x*w0.z + xv.y*w1.z + xv.z*w2.z + xv.w*w3.z;
      acc[r].w += xv.x*w0.w + xv.y*w1.w + xv.z*w2.w + xv.w*w3.w;
    }
  }
#pragma unroll
  for (int r = 0; r < 8; ++r) {
    float4 v = acc[r];
    v.x = fmaxf(v.x, 0.f); v.y = fmaxf(v.y, 0.f);
    v.z = fmaxf(v.z, 0.f); v.w = fmaxf(v.w, 0.f);
    *(float4*)(out + (size_t)(r0+r)*DR + c) = v;
  }
}

// ---------- layer-0 normalize: Q = l2norm(relu(fc(l2norm(P)))) , pad row zeroed ----------
// thread = (node, capsule)
__global__ __launch_bounds__(256) void norm_fc_kernel(
    const float* __restrict__ hin, const float* __restrict__ fcw,
    const float* __restrict__ fcb, float* __restrict__ q) {
  const int gid = blockIdx.x * 256 + threadIdx.x;
  const int n = gid >> 3;
  const int k = gid & 7;
  if (n > NN) return;
  float* qrow = q + (size_t)n * DR + k * DDIM;
  if (n == NN) {  // zero pad row every launch (ws is re-poisoned)
#pragma unroll
    for (int i = 0; i < DDIM; i += 4)
      *(float4*)(qrow + i) = make_float4(0.f, 0.f, 0.f, 0.f);
    return;
  }
  const float* hrow = hin + (size_t)n * DR + k * DDIM;
  float v[DDIM];
  float ss = 0.f;
#pragma unroll
  for (int i = 0; i < DDIM; i += 4) {
    float4 t = *(const float4*)(hrow + i);
    t.x = fmaxf(t.x, 0.f); t.y = fmaxf(t.y, 0.f);
    t.z = fmaxf(t.z, 0.f); t.w = fmaxf(t.w, 0.f);
    v[i] = t.x; v[i+1] = t.y; v[i+2] = t.z; v[i+3] = t.w;
    ss += t.x*t.x + t.y*t.y + t.z*t.z + t.w*t.w;
  }
  float inv = 1.f / fmaxf(sqrtf(ss), 1e-12f);
#pragma unroll
  for (int i = 0; i < DDIM; ++i) v[i] *= inv;
  // per-capsule fc: y[o] = relu(b[k,o] + sum_i v[i]*fcw[k,o,i])
  float y[DDIM];
  ss = 0.f;
  const float* wk = fcw + (size_t)k * DDIM * DDIM;
#pragma unroll 4
  for (int o = 0; o < DDIM; ++o) {
    float a = fcb[k * DDIM + o];
#pragma unroll
    for (int i = 0; i < DDIM; i += 4) {
      const float4 wv = *(const float4*)(wk + o * DDIM + i);
      a += v[i]*wv.x + v[i+1]*wv.y + v[i+2]*wv.z + v[i+3]*wv.w;
    }
    a = fmaxf(a, 0.f);
    y[o] = a;
    ss += a * a;
  }
  inv = 1.f / fmaxf(sqrtf(ss), 1e-12f);
#pragma unroll
  for (int o = 0; o < DDIM; o += 4) {
    float4 t;
    t.x = y[o]*inv; t.y = y[o+1]*inv; t.z = y[o+2]*inv; t.w = y[o+3]*inv;
    *(float4*)(qrow + o) = t;
  }
}

// ---------- layers 1/2 normalize: Q = l2norm(relu(P)) per capsule, pad row zeroed ----------
__global__ __launch_bounds__(256) void norm_relu_kernel(
    const float* __restrict__ hin, float* __restrict__ q) {
  const int gid = blockIdx.x * 256 + threadIdx.x;
  const int n = gid >> 3;
  const int k = gid & 7;
  if (n > NN) return;
  float* qrow = q + (size_t)n * DR + k * DDIM;
  if (n == NN) {
#pragma unroll
    for (int i = 0; i < DDIM; i += 4)
      *(float4*)(qrow + i) = make_float4(0.f, 0.f, 0.f, 0.f);
    return;
  }
  const float* hrow = hin + (size_t)n * DR + k * DDIM;
  float v[DDIM];
  float ss = 0.f;
#pragma unroll
  for (int i = 0; i < DDIM; i += 4) {
    float4 t = *(const float4*)(hrow + i);
    t.x = fmaxf(t.x, 0.f); t.y = fmaxf(t.y, 0.f);
    t.z = fmaxf(t.z, 0.f); t.w = fmaxf(t.w, 0.f);
    v[i] = t.x; v[i+1] = t.y; v[i+2] = t.z; v[i+3] = t.w;
    ss += t.x*t.x + t.y*t.y + t.z*t.z + t.w*t.w;
  }
  const float inv = 1.f / fmaxf(sqrtf(ss), 1e-12f);
#pragma unroll
  for (int i = 0; i < DDIM; i += 4) {
    float4 t;
    t.x = v[i]*inv; t.y = v[i+1]*inv; t.z = v[i+2]*inv; t.w = v[i+3]*inv;
    *(float4*)(qrow + i) = t;
  }
}

// ---------------- routing: wave per node, z in VGPRs ----------------
// lane = k*8 + s ; lane owns dims [s*4, s*4+4) of capsule k.
// d-reductions: shfl_xor {1,2,4} (within capsule group); k-reductions: {8,16,32}.
__global__ __launch_bounds__(256) void routing_kernel(
    const float* __restrict__ q, const int* __restrict__ nbr,
    const float* __restrict__ rawp, const int* __restrict__ ritp,
    float* __restrict__ uout) {
  const int lane = threadIdx.x & 63;
  const int node = blockIdx.x * 4 + (threadIdx.x >> 6);
  const int k = lane >> 3;
  const int s = lane & 7;
  const int off = k * DDIM + s * 4;
  const float param = 1.f / (1.f + __expf(-rawp[0]));
  const float qparam = 1.f - param;
  const int iters = ritp[0];

  float4 z[MMN];
#pragma unroll
  for (int m = 0; m < MMN; ++m) {
    const int j = nbr[node * MMN + m];           // wave-uniform (scalar) load
    z[m] = *(const float4*)(q + (size_t)j * DR + off);  // coalesced 1KB/wave
  }
  float4 ub = *(const float4*)(q + (size_t)node * DR + off);
  float4 u = ub;

  for (int it = 0; it < iters; ++it) {
    float p[MMN];
    if (it == 0) {
#pragma unroll
      for (int m = 0; m < MMN; ++m) p[m] = 0.f;
    } else {
#pragma unroll
      for (int m = 0; m < MMN; ++m) {
        float d = z[m].x*u.x + z[m].y*u.y + z[m].z*u.z + z[m].w*u.w;
        d += __shfl_xor(d, 1);
        d += __shfl_xor(d, 2);
        d += __shfl_xor(d, 4);
        p[m] = d;   // full dot over 32 dims, replicated in capsule group
      }
    }
    // softmax over m (neighbors) — fully local
    float mx = p[0];
#pragma unroll
    for (int m = 1; m < MMN; ++m) mx = fmaxf(mx, p[m]);
    float e1[MMN];
    float sm = 0.f;
#pragma unroll
    for (int m = 0; m < MMN; ++m) { e1[m] = __expf(p[m] - mx); sm += e1[m]; }
    const float c1 = param / sm;
    // softmax over k (capsules) — butterfly across capsule groups
    float mk[MMN];
#pragma unroll
    for (int m = 0; m < MMN; ++m) mk[m] = p[m];
#pragma unroll
    for (int m = 0; m < MMN; ++m) mk[m] = fmaxf(mk[m], __shfl_xor(mk[m], 8));
#pragma unroll
    for (int m = 0; m < MMN; ++m) mk[m] = fmaxf(mk[m], __shfl_xor(mk[m], 16));
#pragma unroll
    for (int m = 0; m < MMN; ++m) mk[m] = fmaxf(mk[m], __shfl_xor(mk[m], 32));
    float e2[MMN], sk[MMN];
#pragma unroll
    for (int m = 0; m < MMN; ++m) { e2[m] = __expf(p[m] - mk[m]); sk[m] = e2[m]; }
#pragma unroll
    for (int m = 0; m < MMN; ++m) sk[m] += __shfl_xor(sk[m], 8);
#pragma unroll
    for (int m = 0; m < MMN; ++m) sk[m] += __shfl_xor(sk[m], 16);
#pragma unroll
    for (int m = 0; m < MMN; ++m) sk[m] += __shfl_xor(sk[m], 32);
    // u = ub + sum_m (param*p1[m] + (1-param)*p2[m]) * z[m]
    float4 un = ub;
#pragma unroll
    for (int m = 0; m < MMN; ++m) {
      const float wm = e1[m]*c1 + qparam*e2[m]/sk[m];
      un.x += wm*z[m].x; un.y += wm*z[m].y; un.z += wm*z[m].z; un.w += wm*z[m].w;
    }
    ub = un;  // u_before tracks UNnormalized u
    if (it < iters - 1) {
      float ss = un.x*un.x + un.y*un.y + un.z*un.z + un.w*un.w;
      ss += __shfl_xor(ss, 1);
      ss += __shfl_xor(ss, 2);
      ss += __shfl_xor(ss, 4);
      const float inv = 1.f / fmaxf(sqrtf(ss), 1e-12f);
      u.x = un.x*inv; u.y = un.y*inv; u.z = un.z*inv; u.w = un.w*inv;
    } else {
      u = un;
    }
  }
  *(float4*)(uout + (size_t)node * DR + off) = ub;  // final u, unnormalized
}

// ---------------- MLP head + log_softmax ----------------
// wave per node: lane = c*4 + qq; qq slices the 256-dim dot into 4x64.
__global__ __launch_bounds__(256) void mlp_kernel(
    const float* __restrict__ h, const float* __restrict__ w,
    const float* __restrict__ b, float* __restrict__ out) {
  const int lane = threadIdx.x & 63;
  const int node = blockIdx.x * 4 + (threadIdx.x >> 6);
  const int c  = lane >> 2;
  const int qq = lane & 3;
  const float* hrow = h + (size_t)node * DR + qq * 64;
  const float* wrow = w + (size_t)c * DR + qq * 64;
  float acc = 0.f;
#pragma unroll
  for (int i = 0; i < 64; i += 4) {
    const float4 hv = *(const float4*)(hrow + i);
    const float4 wv = *(const float4*)(wrow + i);
    acc += hv.x*wv.x + hv.y*wv.y + hv.z*wv.z + hv.w*wv.w;
  }
  acc += __shfl_xor(acc, 1);
  acc += __shfl_xor(acc, 2);
  const float logit = acc + b[c];
  float mx = logit;
  mx = fmaxf(mx, __shfl_xor(mx, 4));
  mx = fmaxf(mx, __shfl_xor(mx, 8));
  mx = fmaxf(mx, __shfl_xor(mx, 16));
  mx = fmaxf(mx, __shfl_xor(mx, 32));
  const float e = __expf(logit - mx);
  float se = e;
  se += __shfl_xor(se, 4);
  se += __shfl_xor(se, 8);
  se += __shfl_xor(se, 16);
  se += __shfl_xor(se, 32);
  const float lp = logit - mx - __logf(se);
  if (qq == 0) out[(size_t)node * NC + c] = lp;
}

extern "C" void kernel_launch(void* const* d_in, const int* in_sizes, int n_in,
                              void* d_out, int out_size, void* d_ws, size_t ws_size,
                              hipStream_t stream) {
  const float* x     = (const float*)d_in[0];   // [30000,1024]
  const int*   nbr   = (const int*)  d_in[1];   // [30000,16]
  const float* pca_w = (const float*)d_in[2];   // [1024,256]
  const float* pca_b = (const float*)d_in[3];   // [256]
  const float* rawp  = (const float*)d_in[4];   // [1]
  const float* fc_w  = (const float*)d_in[5];   // [8,32,32]
  const float* fc_b  = (const float*)d_in[6];   // [8,32]
  const float* mlp_w = (const float*)d_in[7];   // [16,256]
  const float* mlp_b = (const float*)d_in[8];   // [16]
  const int*   ritp  = (const int*)  d_in[9];   // [1] == 6

  float* out = (float*)d_out;                   // log_probs [NN,NC] then h [NN,DR]
  float* H   = out + (size_t)NN * NC;           // embedding region, doubles as ping buffer P
  float* P   = H;                               // alias: P lives in d_out (re-poisoned each call)
  float* Q   = (float*)d_ws;                    // [NN+1, DR] normalized table (+pad row) — only ws user (30.7 MB)

  // PCA + relu
  pca_kernel<<<(NN + 31) / 32, 256, 0, stream>>>(x, pca_w, pca_b, P);
  // layer 0 (with per-capsule fc)
  norm_fc_kernel<<<((NN + 1) * KC + 255) / 256, 256, 0, stream>>>(P, fc_w, fc_b, Q);
  routing_kernel<<<NN / 4, 256, 0, stream>>>(Q, nbr, rawp, ritp, P);
  // layer 1
  norm_relu_kernel<<<((NN + 1) * KC + 255) / 256, 256, 0, stream>>>(P, Q);
  routing_kernel<<<NN / 4, 256, 0, stream>>>(Q, nbr, rawp, ritp, P);
  // layer 2 (writes final embedding straight into d_out)
  norm_relu_kernel<<<((NN + 1) * KC + 255) / 256, 256, 0, stream>>>(P, Q);
  routing_kernel<<<NN / 4, 256, 0, stream>>>(Q, nbr, rawp, ritp, H);
  // classifier head
  mlp_kernel<<<NN / 4, 256, 0, stream>>>(H, mlp_w, mlp_b, out);
}

// Round 3
// 1070.843 us; speedup vs baseline: 1.8629x; 1.8629x over previous
//
#include <hip/hip_runtime.h>

#define NN 30000   // nodes
#define MMN 16     // neighbors
#define NF 1024    // input features
#define NC 16      // classes
#define KC 8       // capsules
#define DDIM 32    // dims per capsule
#define DR 256     // rep dim

typedef __bf16 bf16x8 __attribute__((ext_vector_type(8)));
typedef float floatx4 __attribute__((ext_vector_type(4)));

__device__ inline void splitbf(float v, __bf16& h, __bf16& l) {
  h = (__bf16)v;                 // RNE
  l = (__bf16)(v - (float)h);    // residual
}

// ---------------- wt_build: split-transpose w [1024,256] -> wt_hi/wt_lo [256,1024] bf16 ----------------
// wt lives in the log_probs region of d_out (dead until mlp_kernel overwrites it at the end).
__global__ __launch_bounds__(256) void wt_build_kernel(
    const float* __restrict__ w, __bf16* __restrict__ wt_hi, __bf16* __restrict__ wt_lo) {
  const int gid = blockIdx.x * 256 + threadIdx.x;  // 32768 threads
  const int c  = gid >> 7;        // 0..255
  const int k0 = (gid & 127) << 3;
  bf16x8 h, l;
#pragma unroll
  for (int j = 0; j < 8; ++j) {
    const float v = w[(size_t)(k0 + j) * DR + c];  // strided read, w is 1MB L2-hot
    __bf16 hh, ll; splitbf(v, hh, ll);
    h[j] = hh; l[j] = ll;
  }
  *(bf16x8*)(wt_hi + (size_t)c * NF + k0) = h;     // coalesced 16B store
  *(bf16x8*)(wt_lo + (size_t)c * NF + k0) = l;
}

// ---------------- PCA via split-bf16 MFMA: P = relu(x @ w + b) ----------------
// Block: 128 rows x 64 cols, 4 waves; wave: 32x64 (2 rowtiles x 4 coltiles of 16x16).
// 3 MFMAs per tile per K-chunk (hh, hl, lh) -> fp32-equivalent precision (err ~2^-18).
__global__ __launch_bounds__(256) void pca_mfma_kernel(
    const float* __restrict__ x, const __bf16* __restrict__ wt_hi,
    const __bf16* __restrict__ wt_lo, const float* __restrict__ b,
    float* __restrict__ out) {
  __shared__ __bf16 Ah[128][40];   // pad 8 bf16 -> stride 80B: frag reads 2-way (free)
  __shared__ __bf16 Al[128][40];
  const int t    = threadIdx.x;
  const int lane = t & 63;
  const int wv   = t >> 6;
  const int q    = lane >> 4;      // quad 0..3
  const int lm   = lane & 15;
  const int rowBase = (blockIdx.x >> 2) << 7;
  const int colBase = (blockIdx.x & 3) << 6;

  const int sr = t >> 1;           // staging row 0..127
  const int sk = (t & 1) << 4;     // staging k-offset 0/16

  floatx4 acc[2][4];
#pragma unroll
  for (int rt = 0; rt < 2; ++rt)
#pragma unroll
    for (int ct = 0; ct < 4; ++ct)
      acc[rt][ct] = (floatx4){0.f, 0.f, 0.f, 0.f};

  const float* xrow = x + (size_t)(rowBase + sr) * NF + sk;
  const bool srOK = (rowBase + sr) < NN;

  for (int k0 = 0; k0 < NF; k0 += 32) {
    // B fragments straight from global (wt is 1MB, L2-hot; reused by all row-blocks)
    bf16x8 bh[4], bl[4];
#pragma unroll
    for (int ct = 0; ct < 4; ++ct) {
      const int n = colBase + (ct << 4) + lm;
      bh[ct] = *(const bf16x8*)(wt_hi + (size_t)n * NF + k0 + (q << 3));
      bl[ct] = *(const bf16x8*)(wt_lo + (size_t)n * NF + k0 + (q << 3));
    }
    // A tile global load (issued before barrier for overlap)
    float4 xv[4];
    if (srOK) {
#pragma unroll
      for (int i = 0; i < 4; ++i) xv[i] = *(const float4*)(xrow + k0 + 4 * i);
    } else {
#pragma unroll
      for (int i = 0; i < 4; ++i) xv[i] = make_float4(0.f, 0.f, 0.f, 0.f);
    }
    __syncthreads();  // previous chunk's frag reads done
    {
      const float vs[16] = {xv[0].x, xv[0].y, xv[0].z, xv[0].w,
                            xv[1].x, xv[1].y, xv[1].z, xv[1].w,
                            xv[2].x, xv[2].y, xv[2].z, xv[2].w,
                            xv[3].x, xv[3].y, xv[3].z, xv[3].w};
      bf16x8 h0, l0, h1, l1;
#pragma unroll
      for (int j = 0; j < 8; ++j) { __bf16 H, L; splitbf(vs[j], H, L);     h0[j] = H; l0[j] = L; }
#pragma unroll
      for (int j = 0; j < 8; ++j) { __bf16 H, L; splitbf(vs[8 + j], H, L); h1[j] = H; l1[j] = L; }
      *(bf16x8*)&Ah[sr][sk]     = h0;
      *(bf16x8*)&Ah[sr][sk + 8] = h1;
      *(bf16x8*)&Al[sr][sk]     = l0;
      *(bf16x8*)&Al[sr][sk + 8] = l1;
    }
    __syncthreads();  // writes visible
#pragma unroll
    for (int rt = 0; rt < 2; ++rt) {
      const int ar = (wv << 5) + (rt << 4) + lm;
      const bf16x8 ah = *(const bf16x8*)&Ah[ar][q << 3];
      const bf16x8 al = *(const bf16x8*)&Al[ar][q << 3];
#pragma unroll
      for (int ct = 0; ct < 4; ++ct) {
        acc[rt][ct] = __builtin_amdgcn_mfma_f32_16x16x32_bf16(ah, bh[ct], acc[rt][ct], 0, 0, 0);
        acc[rt][ct] = __builtin_amdgcn_mfma_f32_16x16x32_bf16(ah, bl[ct], acc[rt][ct], 0, 0, 0);
        acc[rt][ct] = __builtin_amdgcn_mfma_f32_16x16x32_bf16(al, bh[ct], acc[rt][ct], 0, 0, 0);
      }
    }
  }
  // epilogue: bias + relu; C/D layout col=lane&15, row=quad*4+reg (m89/m91-verified)
#pragma unroll
  for (int rt = 0; rt < 2; ++rt) {
#pragma unroll
    for (int ct = 0; ct < 4; ++ct) {
      const int col = colBase + (ct << 4) + lm;
      const float bias = b[col];
#pragma unroll
      for (int r = 0; r < 4; ++r) {
        const int row = rowBase + (wv << 5) + (rt << 4) + (q << 2) + r;
        if (row < NN) out[(size_t)row * DR + col] = fmaxf(acc[rt][ct][r] + bias, 0.f);
      }
    }
  }
}

// ---------- layer-0 normalize: Q = l2norm(relu(fc(l2norm(P)))) , pad row zeroed ----------
__global__ __launch_bounds__(256) void norm_fc_kernel(
    const float* __restrict__ hin, const float* __restrict__ fcw,
    const float* __restrict__ fcb, float* __restrict__ q) {
  const int gid = blockIdx.x * 256 + threadIdx.x;
  const int n = gid >> 3;
  const int k = gid & 7;
  if (n > NN) return;
  float* qrow = q + (size_t)n * DR + k * DDIM;
  if (n == NN) {
#pragma unroll
    for (int i = 0; i < DDIM; i += 4)
      *(float4*)(qrow + i) = make_float4(0.f, 0.f, 0.f, 0.f);
    return;
  }
  const float* hrow = hin + (size_t)n * DR + k * DDIM;
  float v[DDIM];
  float ss = 0.f;
#pragma unroll
  for (int i = 0; i < DDIM; i += 4) {
    float4 tv = *(const float4*)(hrow + i);
    tv.x = fmaxf(tv.x, 0.f); tv.y = fmaxf(tv.y, 0.f);
    tv.z = fmaxf(tv.z, 0.f); tv.w = fmaxf(tv.w, 0.f);
    v[i] = tv.x; v[i+1] = tv.y; v[i+2] = tv.z; v[i+3] = tv.w;
    ss += tv.x*tv.x + tv.y*tv.y + tv.z*tv.z + tv.w*tv.w;
  }
  float inv = 1.f / fmaxf(sqrtf(ss), 1e-12f);
#pragma unroll
  for (int i = 0; i < DDIM; ++i) v[i] *= inv;
  float y[DDIM];
  ss = 0.f;
  const float* wk = fcw + (size_t)k * DDIM * DDIM;
#pragma unroll 4
  for (int o = 0; o < DDIM; ++o) {
    float a = fcb[k * DDIM + o];
#pragma unroll
    for (int i = 0; i < DDIM; i += 4) {
      const float4 wv = *(const float4*)(wk + o * DDIM + i);
      a += v[i]*wv.x + v[i+1]*wv.y + v[i+2]*wv.z + v[i+3]*wv.w;
    }
    a = fmaxf(a, 0.f);
    y[o] = a;
    ss += a * a;
  }
  inv = 1.f / fmaxf(sqrtf(ss), 1e-12f);
#pragma unroll
  for (int o = 0; o < DDIM; o += 4) {
    float4 tv;
    tv.x = y[o]*inv; tv.y = y[o+1]*inv; tv.z = y[o+2]*inv; tv.w = y[o+3]*inv;
    *(float4*)(qrow + o) = tv;
  }
}

// ---------- layers 1/2 normalize: Q = l2norm(relu(P)) per capsule, pad row zeroed ----------
__global__ __launch_bounds__(256) void norm_relu_kernel(
    const float* __restrict__ hin, float* __restrict__ q) {
  const int gid = blockIdx.x * 256 + threadIdx.x;
  const int n = gid >> 3;
  const int k = gid & 7;
  if (n > NN) return;
  float* qrow = q + (size_t)n * DR + k * DDIM;
  if (n == NN) {
#pragma unroll
    for (int i = 0; i < DDIM; i += 4)
      *(float4*)(qrow + i) = make_float4(0.f, 0.f, 0.f, 0.f);
    return;
  }
  const float* hrow = hin + (size_t)n * DR + k * DDIM;
  float v[DDIM];
  float ss = 0.f;
#pragma unroll
  for (int i = 0; i < DDIM; i += 4) {
    float4 tv = *(const float4*)(hrow + i);
    tv.x = fmaxf(tv.x, 0.f); tv.y = fmaxf(tv.y, 0.f);
    tv.z = fmaxf(tv.z, 0.f); tv.w = fmaxf(tv.w, 0.f);
    v[i] = tv.x; v[i+1] = tv.y; v[i+2] = tv.z; v[i+3] = tv.w;
    ss += tv.x*tv.x + tv.y*tv.y + tv.z*tv.z + tv.w*tv.w;
  }
  const float inv = 1.f / fmaxf(sqrtf(ss), 1e-12f);
#pragma unroll
  for (int i = 0; i < DDIM; i += 4) {
    float4 tv;
    tv.x = v[i]*inv; tv.y = v[i+1]*inv; tv.z = v[i+2]*inv; tv.w = v[i+3]*inv;
    *(float4*)(qrow + i) = tv;
  }
}

// ---------------- routing: wave per node, z in VGPRs ----------------
// No max-subtraction needed: z,u unit-norm per capsule => |p|<=1, exp(p) in [0.37, 2.72].
// e1 == e2 (same exp), so one exp per (m); rcp instead of divide.
__global__ __launch_bounds__(256) void routing_kernel(
    const float* __restrict__ q, const int* __restrict__ nbr,
    const float* __restrict__ rawp, const int* __restrict__ ritp,
    float* __restrict__ uout) {
  const int lane = threadIdx.x & 63;
  const int node = blockIdx.x * 4 + (threadIdx.x >> 6);
  const int k = lane >> 3;
  const int s = lane & 7;
  const int off = k * DDIM + s * 4;
  const float param = 1.f / (1.f + __expf(-rawp[0]));
  const float qparam = 1.f - param;
  const int iters = ritp[0];

  float4 z[MMN];
#pragma unroll
  for (int m = 0; m < MMN; ++m) {
    const int j = nbr[node * MMN + m];           // wave-uniform (scalar) load
    z[m] = *(const float4*)(q + (size_t)j * DR + off);
  }
  float4 ub = *(const float4*)(q + (size_t)node * DR + off);
  float4 u = ub;

  for (int it = 0; it < iters; ++it) {
    float e[MMN];  // exp(p[m]) for this lane's capsule (replicated over s)
    if (it == 0) {
#pragma unroll
      for (int m = 0; m < MMN; ++m) e[m] = 1.f;
    } else {
#pragma unroll
      for (int m = 0; m < MMN; ++m) {
        float d = z[m].x*u.x + z[m].y*u.y + z[m].z*u.z + z[m].w*u.w;
        d += __shfl_xor(d, 1);
        d += __shfl_xor(d, 2);
        d += __shfl_xor(d, 4);
        e[m] = __expf(d);
      }
    }
    float sm = 0.f;
#pragma unroll
    for (int m = 0; m < MMN; ++m) sm += e[m];
    float sk[MMN];
#pragma unroll
    for (int m = 0; m < MMN; ++m) sk[m] = e[m];
#pragma unroll
    for (int m = 0; m < MMN; ++m) sk[m] += __shfl_xor(sk[m], 8);
#pragma unroll
    for (int m = 0; m < MMN; ++m) sk[m] += __shfl_xor(sk[m], 16);
#pragma unroll
    for (int m = 0; m < MMN; ++m) sk[m] += __shfl_xor(sk[m], 32);
    const float c1 = param * __builtin_amdgcn_rcpf(sm);
    float4 un = ub;
#pragma unroll
    for (int m = 0; m < MMN; ++m) {
      const float wm = e[m] * (c1 + qparam * __builtin_amdgcn_rcpf(sk[m]));
      un.x += wm*z[m].x; un.y += wm*z[m].y; un.z += wm*z[m].z; un.w += wm*z[m].w;
    }
    ub = un;
    if (it < iters - 1) {
      float ss = un.x*un.x + un.y*un.y + un.z*un.z + un.w*un.w;
      ss += __shfl_xor(ss, 1);
      ss += __shfl_xor(ss, 2);
      ss += __shfl_xor(ss, 4);
      const float inv = 1.f / fmaxf(sqrtf(ss), 1e-12f);
      u.x = un.x*inv; u.y = un.y*inv; u.z = un.z*inv; u.w = un.w*inv;
    } else {
      u = un;
    }
  }
  *(float4*)(uout + (size_t)node * DR + off) = ub;
}

// ---------------- MLP head + log_softmax ----------------
__global__ __launch_bounds__(256) void mlp_kernel(
    const float* __restrict__ h, const float* __restrict__ w,
    const float* __restrict__ b, float* __restrict__ out) {
  const int lane = threadIdx.x & 63;
  const int node = blockIdx.x * 4 + (threadIdx.x >> 6);
  const int c  = lane >> 2;
  const int qq = lane & 3;
  const float* hrow = h + (size_t)node * DR + qq * 64;
  const float* wrow = w + (size_t)c * DR + qq * 64;
  float acc = 0.f;
#pragma unroll
  for (int i = 0; i < 64; i += 4) {
    const float4 hv = *(const float4*)(hrow + i);
    const float4 wv = *(const float4*)(wrow + i);
    acc += hv.x*wv.x + hv.y*wv.y + hv.z*wv.z + hv.w*wv.w;
  }
  acc += __shfl_xor(acc, 1);
  acc += __shfl_xor(acc, 2);
  const float logit = acc + b[c];
  float mx = logit;
  mx = fmaxf(mx, __shfl_xor(mx, 4));
  mx = fmaxf(mx, __shfl_xor(mx, 8));
  mx = fmaxf(mx, __shfl_xor(mx, 16));
  mx = fmaxf(mx, __shfl_xor(mx, 32));
  const float e = __expf(logit - mx);
  float se = e;
  se += __shfl_xor(se, 4);
  se += __shfl_xor(se, 8);
  se += __shfl_xor(se, 16);
  se += __shfl_xor(se, 32);
  const float lp = logit - mx - __logf(se);
  if (qq == 0) out[(size_t)node * NC + c] = lp;
}

extern "C" void kernel_launch(void* const* d_in, const int* in_sizes, int n_in,
                              void* d_out, int out_size, void* d_ws, size_t ws_size,
                              hipStream_t stream) {
  const float* x     = (const float*)d_in[0];   // [30000,1024]
  const int*   nbr   = (const int*)  d_in[1];   // [30000,16]
  const float* pca_w = (const float*)d_in[2];   // [1024,256]
  const float* pca_b = (const float*)d_in[3];   // [256]
  const float* rawp  = (const float*)d_in[4];   // [1]
  const float* fc_w  = (const float*)d_in[5];   // [8,32,32]
  const float* fc_b  = (const float*)d_in[6];   // [8,32]
  const float* mlp_w = (const float*)d_in[7];   // [16,256]
  const float* mlp_b = (const float*)d_in[8];   // [16]
  const int*   ritp  = (const int*)  d_in[9];   // [1] == 6

  float* out = (float*)d_out;                   // log_probs [NN,NC] then h [NN,DR]
  float* H   = out + (size_t)NN * NC;           // embedding region == ping buffer P
  float* P   = H;
  float* Q   = (float*)d_ws;                    // [NN+1, DR] normalized table (30.7 MB)

  // wt scratch lives in the log_probs region (1 MB of 1.92 MB); mlp_kernel
  // overwrites the whole region at the end, so it's dead space until then.
  __bf16* wt_hi = (__bf16*)d_out;               // [256][1024]
  __bf16* wt_lo = wt_hi + (size_t)DR * NF;      // [256][1024]

  wt_build_kernel<<<128, 256, 0, stream>>>(pca_w, wt_hi, wt_lo);
  pca_mfma_kernel<<<((NN + 127) / 128) * 4, 256, 0, stream>>>(x, wt_hi, wt_lo, pca_b, P);
  // layer 0 (with per-capsule fc)
  norm_fc_kernel<<<((NN + 1) * KC + 255) / 256, 256, 0, stream>>>(P, fc_w, fc_b, Q);
  routing_kernel<<<NN / 4, 256, 0, stream>>>(Q, nbr, rawp, ritp, P);
  // layer 1
  norm_relu_kernel<<<((NN + 1) * KC + 255) / 256, 256, 0, stream>>>(P, Q);
  routing_kernel<<<NN / 4, 256, 0, stream>>>(Q, nbr, rawp, ritp, P);
  // layer 2 (writes final embedding straight into d_out)
  norm_relu_kernel<<<((NN + 1) * KC + 255) / 256, 256, 0, stream>>>(P, Q);
  routing_kernel<<<NN / 4, 256, 0, stream>>>(Q, nbr, rawp, ritp, H);
  // classifier head (overwrites wt scratch with log_probs)
  mlp_kernel<<<NN / 4, 256, 0, stream>>>(H, mlp_w, mlp_b, out);
}

// Round 4
// 1040.205 us; speedup vs baseline: 1.9178x; 1.0295x over previous
//
#include <hip/hip_runtime.h>

#define NN 30000   // nodes
#define MMN 16     // neighbors
#define NF 1024    // input features
#define NC 16      // classes
#define KC 8       // capsules
#define DDIM 32    // dims per capsule
#define DR 256     // rep dim

typedef __bf16 bf16x8 __attribute__((ext_vector_type(8)));
typedef float floatx4 __attribute__((ext_vector_type(4)));

__device__ inline void splitbf(float v, __bf16& h, __bf16& l) {
  h = (__bf16)v;                 // RNE
  l = (__bf16)(v - (float)h);    // residual
}

// ---------------- wt_build: split-transpose w [1024,256] -> wt_hi/wt_lo [256,1024] bf16 ----------------
__global__ __launch_bounds__(256) void wt_build_kernel(
    const float* __restrict__ w, __bf16* __restrict__ wt_hi, __bf16* __restrict__ wt_lo) {
  const int gid = blockIdx.x * 256 + threadIdx.x;  // 32768 threads
  const int c  = gid >> 7;        // 0..255
  const int k0 = (gid & 127) << 3;
  bf16x8 h, l;
#pragma unroll
  for (int j = 0; j < 8; ++j) {
    const float v = w[(size_t)(k0 + j) * DR + c];
    __bf16 hh, ll; splitbf(v, hh, ll);
    h[j] = hh; l[j] = ll;
  }
  *(bf16x8*)(wt_hi + (size_t)c * NF + k0) = h;
  *(bf16x8*)(wt_lo + (size_t)c * NF + k0) = l;
}

// ---------------- pad_zero: zero the pad-first row of table B (256 floats) ----------------
__global__ void pad_zero_kernel(float* __restrict__ p) {
  ((float4*)p)[threadIdx.x] = make_float4(0.f, 0.f, 0.f, 0.f);  // 64 threads x 16B
}

// ---------------- PCA via split-bf16 MFMA: P = relu(x @ w + b) ----------------
// Block: 128 rows x 64 cols; 3 MFMAs (hh,hl,lh) per tile per K-chunk; x-prefetch pipelined.
__global__ __launch_bounds__(256) void pca_mfma_kernel(
    const float* __restrict__ x, const __bf16* __restrict__ wt_hi,
    const __bf16* __restrict__ wt_lo, const float* __restrict__ b,
    float* __restrict__ out) {
  __shared__ __bf16 Ah[128][40];
  __shared__ __bf16 Al[128][40];
  const int t    = threadIdx.x;
  const int lane = t & 63;
  const int wv   = t >> 6;
  const int q    = lane >> 4;
  const int lm   = lane & 15;
  const int rowBase = (blockIdx.x >> 2) << 7;
  const int colBase = (blockIdx.x & 3) << 6;

  const int sr = t >> 1;
  const int sk = (t & 1) << 4;

  floatx4 acc[2][4];
#pragma unroll
  for (int rt = 0; rt < 2; ++rt)
#pragma unroll
    for (int ct = 0; ct < 4; ++ct)
      acc[rt][ct] = (floatx4){0.f, 0.f, 0.f, 0.f};

  const float* xrow = x + (size_t)(rowBase + sr) * NF + sk;
  const bool srOK = (rowBase + sr) < NN;

  float4 xv[4];
  if (srOK) {
#pragma unroll
    for (int i = 0; i < 4; ++i) xv[i] = *(const float4*)(xrow + 4 * i);
  } else {
#pragma unroll
    for (int i = 0; i < 4; ++i) xv[i] = make_float4(0.f, 0.f, 0.f, 0.f);
  }

  for (int k0 = 0; k0 < NF; k0 += 32) {
    bf16x8 bh[4], bl[4];
#pragma unroll
    for (int ct = 0; ct < 4; ++ct) {
      const int n = colBase + (ct << 4) + lm;
      bh[ct] = *(const bf16x8*)(wt_hi + (size_t)n * NF + k0 + (q << 3));
      bl[ct] = *(const bf16x8*)(wt_lo + (size_t)n * NF + k0 + (q << 3));
    }
    __syncthreads();  // prior chunk's frag reads done before LDS overwrite
    {
      const float vs[16] = {xv[0].x, xv[0].y, xv[0].z, xv[0].w,
                            xv[1].x, xv[1].y, xv[1].z, xv[1].w,
                            xv[2].x, xv[2].y, xv[2].z, xv[2].w,
                            xv[3].x, xv[3].y, xv[3].z, xv[3].w};
      bf16x8 h0, l0, h1, l1;
#pragma unroll
      for (int j = 0; j < 8; ++j) { __bf16 H, L; splitbf(vs[j], H, L);     h0[j] = H; l0[j] = L; }
#pragma unroll
      for (int j = 0; j < 8; ++j) { __bf16 H, L; splitbf(vs[8 + j], H, L); h1[j] = H; l1[j] = L; }
      *(bf16x8*)&Ah[sr][sk]     = h0;
      *(bf16x8*)&Ah[sr][sk + 8] = h1;
      *(bf16x8*)&Al[sr][sk]     = l0;
      *(bf16x8*)&Al[sr][sk + 8] = l1;
    }
    // prefetch next x chunk — consumed after next barrier, full chunk of latency cover
    float4 xn[4];
    if (k0 + 32 < NF && srOK) {
#pragma unroll
      for (int i = 0; i < 4; ++i) xn[i] = *(const float4*)(xrow + k0 + 32 + 4 * i);
    } else {
#pragma unroll
      for (int i = 0; i < 4; ++i) xn[i] = make_float4(0.f, 0.f, 0.f, 0.f);
    }
    __syncthreads();
#pragma unroll
    for (int rt = 0; rt < 2; ++rt) {
      const int ar = (wv << 5) + (rt << 4) + lm;
      const bf16x8 ah = *(const bf16x8*)&Ah[ar][q << 3];
      const bf16x8 al = *(const bf16x8*)&Al[ar][q << 3];
#pragma unroll
      for (int ct = 0; ct < 4; ++ct) {
        acc[rt][ct] = __builtin_amdgcn_mfma_f32_16x16x32_bf16(ah, bh[ct], acc[rt][ct], 0, 0, 0);
        acc[rt][ct] = __builtin_amdgcn_mfma_f32_16x16x32_bf16(ah, bl[ct], acc[rt][ct], 0, 0, 0);
        acc[rt][ct] = __builtin_amdgcn_mfma_f32_16x16x32_bf16(al, bh[ct], acc[rt][ct], 0, 0, 0);
      }
    }
#pragma unroll
    for (int i = 0; i < 4; ++i) xv[i] = xn[i];
  }
  // epilogue: bias + relu; C/D layout col=lane&15, row=quad*4+reg
#pragma unroll
  for (int rt = 0; rt < 2; ++rt) {
#pragma unroll
    for (int ct = 0; ct < 4; ++ct) {
      const int col = colBase + (ct << 4) + lm;
      const float bias = b[col];
#pragma unroll
      for (int r = 0; r < 4; ++r) {
        const int row = rowBase + (wv << 5) + (rt << 4) + (q << 2) + r;
        if (row < NN) out[(size_t)row * DR + col] = fmaxf(acc[rt][ct][r] + bias, 0.f);
      }
    }
  }
}

// ---------- layer-0 normalize: Q = l2norm(relu(fc(l2norm(P)))) , pad row NN zeroed ----------
__global__ __launch_bounds__(256) void norm_fc_kernel(
    const float* __restrict__ hin, const float* __restrict__ fcw,
    const float* __restrict__ fcb, float* __restrict__ q) {
  const int gid = blockIdx.x * 256 + threadIdx.x;
  const int n = gid >> 3;
  const int k = gid & 7;
  if (n > NN) return;
  float* qrow = q + (size_t)n * DR + k * DDIM;
  if (n == NN) {
#pragma unroll
    for (int i = 0; i < DDIM; i += 4)
      *(float4*)(qrow + i) = make_float4(0.f, 0.f, 0.f, 0.f);
    return;
  }
  const float* hrow = hin + (size_t)n * DR + k * DDIM;
  float v[DDIM];
  float ss = 0.f;
#pragma unroll
  for (int i = 0; i < DDIM; i += 4) {
    float4 tv = *(const float4*)(hrow + i);
    tv.x = fmaxf(tv.x, 0.f); tv.y = fmaxf(tv.y, 0.f);
    tv.z = fmaxf(tv.z, 0.f); tv.w = fmaxf(tv.w, 0.f);
    v[i] = tv.x; v[i+1] = tv.y; v[i+2] = tv.z; v[i+3] = tv.w;
    ss += tv.x*tv.x + tv.y*tv.y + tv.z*tv.z + tv.w*tv.w;
  }
  float inv = 1.f / fmaxf(sqrtf(ss), 1e-12f);
#pragma unroll
  for (int i = 0; i < DDIM; ++i) v[i] *= inv;
  float y[DDIM];
  ss = 0.f;
  const float* wk = fcw + (size_t)k * DDIM * DDIM;
#pragma unroll 4
  for (int o = 0; o < DDIM; ++o) {
    float a = fcb[k * DDIM + o];
#pragma unroll
    for (int i = 0; i < DDIM; i += 4) {
      const float4 wv = *(const float4*)(wk + o * DDIM + i);
      a += v[i]*wv.x + v[i+1]*wv.y + v[i+2]*wv.z + v[i+3]*wv.w;
    }
    a = fmaxf(a, 0.f);
    y[o] = a;
    ss += a * a;
  }
  inv = 1.f / fmaxf(sqrtf(ss), 1e-12f);
#pragma unroll
  for (int o = 0; o < DDIM; o += 4) {
    float4 tv;
    tv.x = y[o]*inv; tv.y = y[o+1]*inv; tv.z = y[o+2]*inv; tv.w = y[o+3]*inv;
    *(float4*)(qrow + o) = tv;
  }
}

// ---------------- routing: wave per node, z in VGPRs (launch_bounds(256,3): no spill) ----------------
// tab: gather table (rows j); padrow: the zero row for j==NN.
// doNorm=1: epilogue writes l2norm(relu(u)) (fused inter-layer normalize); 0: raw u.
__global__ __launch_bounds__(256, 3) void routing_kernel(
    const float* __restrict__ tab, const float* __restrict__ padrow,
    const int* __restrict__ nbr, const float* __restrict__ rawp,
    const int* __restrict__ ritp, float* __restrict__ uout, const int doNorm) {
  const int lane = threadIdx.x & 63;
  const int node = blockIdx.x * 4 + (threadIdx.x >> 6);
  const int off = (lane >> 3) * DDIM + (lane & 7) * 4;
  const float param = 1.f / (1.f + __expf(-rawp[0]));
  const float qparam = 1.f - param;
  const int iters = ritp[0];

  float4 z[MMN];
#pragma unroll
  for (int m = 0; m < MMN; ++m) {
    const int j = nbr[node * MMN + m];                    // wave-uniform
    const float* zrow = (j == NN) ? padrow : (tab + (size_t)j * DR);
    z[m] = *(const float4*)(zrow + off);
  }
  float4 ub = *(const float4*)(tab + (size_t)node * DR + off);
  float4 u = ub;

  for (int it = 0; it < iters; ++it) {
    float e[MMN];  // exp(p[m]); no max-subtraction needed: |p|<=1 (unit-norm dots)
    if (it == 0) {
#pragma unroll
      for (int m = 0; m < MMN; ++m) e[m] = 1.f;
    } else {
#pragma unroll
      for (int m = 0; m < MMN; ++m) {
        float d = z[m].x*u.x + z[m].y*u.y + z[m].z*u.z + z[m].w*u.w;
        d += __shfl_xor(d, 1);
        d += __shfl_xor(d, 2);
        d += __shfl_xor(d, 4);
        e[m] = __expf(d);
      }
    }
    float sm = 0.f;
#pragma unroll
    for (int m = 0; m < MMN; ++m) sm += e[m];
    float sk[MMN];
#pragma unroll
    for (int m = 0; m < MMN; ++m) sk[m] = e[m];
#pragma unroll
    for (int m = 0; m < MMN; ++m) sk[m] += __shfl_xor(sk[m], 8);
#pragma unroll
    for (int m = 0; m < MMN; ++m) sk[m] += __shfl_xor(sk[m], 16);
#pragma unroll
    for (int m = 0; m < MMN; ++m) sk[m] += __shfl_xor(sk[m], 32);
    const float c1 = param * __builtin_amdgcn_rcpf(sm);
    float4 un = ub;
#pragma unroll
    for (int m = 0; m < MMN; ++m) {
      const float wm = e[m] * (c1 + qparam * __builtin_amdgcn_rcpf(sk[m]));
      un.x += wm*z[m].x; un.y += wm*z[m].y; un.z += wm*z[m].z; un.w += wm*z[m].w;
    }
    ub = un;
    if (it < iters - 1) {
      float ss = un.x*un.x + un.y*un.y + un.z*un.z + un.w*un.w;
      ss += __shfl_xor(ss, 1);
      ss += __shfl_xor(ss, 2);
      ss += __shfl_xor(ss, 4);
      const float inv = 1.f / fmaxf(sqrtf(ss), 1e-12f);
      u.x = un.x*inv; u.y = un.y*inv; u.z = un.z*inv; u.w = un.w*inv;
    } else {
      u = un;
    }
  }
  float4 w = ub;
  if (doNorm) {  // fused next-layer prep: l2norm(relu(u)) per capsule
    w.x = fmaxf(w.x, 0.f); w.y = fmaxf(w.y, 0.f);
    w.z = fmaxf(w.z, 0.f); w.w = fmaxf(w.w, 0.f);
    float ss = w.x*w.x + w.y*w.y + w.z*w.z + w.w*w.w;
    ss += __shfl_xor(ss, 1);
    ss += __shfl_xor(ss, 2);
    ss += __shfl_xor(ss, 4);
    const float inv = 1.f / fmaxf(sqrtf(ss), 1e-12f);
    w.x *= inv; w.y *= inv; w.z *= inv; w.w *= inv;
  }
  *(float4*)(uout + (size_t)node * DR + off) = w;
}

// ---------------- MLP head + log_softmax ----------------
__global__ __launch_bounds__(256) void mlp_kernel(
    const float* __restrict__ h, const float* __restrict__ w,
    const float* __restrict__ b, float* __restrict__ out) {
  const int lane = threadIdx.x & 63;
  const int node = blockIdx.x * 4 + (threadIdx.x >> 6);
  const int c  = lane >> 2;
  const int qq = lane & 3;
  const float* hrow = h + (size_t)node * DR + qq * 64;
  const float* wrow = w + (size_t)c * DR + qq * 64;
  float acc = 0.f;
#pragma unroll
  for (int i = 0; i < 64; i += 4) {
    const float4 hv = *(const float4*)(hrow + i);
    const float4 wv = *(const float4*)(wrow + i);
    acc += hv.x*wv.x + hv.y*wv.y + hv.z*wv.z + hv.w*wv.w;
  }
  acc += __shfl_xor(acc, 1);
  acc += __shfl_xor(acc, 2);
  const float logit = acc + b[c];
  float mx = logit;
  mx = fmaxf(mx, __shfl_xor(mx, 4));
  mx = fmaxf(mx, __shfl_xor(mx, 8));
  mx = fmaxf(mx, __shfl_xor(mx, 16));
  mx = fmaxf(mx, __shfl_xor(mx, 32));
  const float e = __expf(logit - mx);
  float se = e;
  se += __shfl_xor(se, 4);
  se += __shfl_xor(se, 8);
  se += __shfl_xor(se, 16);
  se += __shfl_xor(se, 32);
  const float lp = logit - mx - __logf(se);
  if (qq == 0) out[(size_t)node * NC + c] = lp;
}

extern "C" void kernel_launch(void* const* d_in, const int* in_sizes, int n_in,
                              void* d_out, int out_size, void* d_ws, size_t ws_size,
                              hipStream_t stream) {
  const float* x     = (const float*)d_in[0];
  const int*   nbr   = (const int*)  d_in[1];
  const float* pca_w = (const float*)d_in[2];
  const float* pca_b = (const float*)d_in[3];
  const float* rawp  = (const float*)d_in[4];
  const float* fc_w  = (const float*)d_in[5];
  const float* fc_b  = (const float*)d_in[6];
  const float* mlp_w = (const float*)d_in[7];
  const float* mlp_b = (const float*)d_in[8];
  const int*   ritp  = (const int*)  d_in[9];

  float* out  = (float*)d_out;                  // log_probs [NN,NC] then h [NN,DR]
  float* EMB  = out + (size_t)NN * NC;          // embedding region; also ping table B rows
  float* Bpad = EMB - DR;                       // table-B zero row (last 1KB of log_probs region, dead until mlp)
  float* Q    = (float*)d_ws;                   // [NN+1, DR] table A (+pad row NN)
  float* Qpad = Q + (size_t)NN * DR;

  // wt scratch: first 1MB of log_probs region (disjoint from Bpad; dead until mlp)
  __bf16* wt_hi = (__bf16*)d_out;               // [256][1024]
  __bf16* wt_lo = wt_hi + (size_t)DR * NF;

  wt_build_kernel<<<128, 256, 0, stream>>>(pca_w, wt_hi, wt_lo);
  pad_zero_kernel<<<1, 64, 0, stream>>>(Bpad);
  // PCA + relu -> raw h rows at EMB
  pca_mfma_kernel<<<((NN + 127) / 128) * 4, 256, 0, stream>>>(x, wt_hi, wt_lo, pca_b, EMB);
  // layer 0 prep (per-capsule fc) -> Q
  norm_fc_kernel<<<((NN + 1) * KC + 255) / 256, 256, 0, stream>>>(EMB, fc_w, fc_b, Q);
  // L0: Q -> B (normalized epilogue)
  routing_kernel<<<NN / 4, 256, 0, stream>>>(Q, Qpad, nbr, rawp, ritp, EMB, 1);
  // L1: B -> Q (normalized epilogue)
  routing_kernel<<<NN / 4, 256, 0, stream>>>(EMB, Bpad, nbr, rawp, ritp, Q, 1);
  // L2: Q -> EMB raw (final embedding)
  routing_kernel<<<NN / 4, 256, 0, stream>>>(Q, Qpad, nbr, rawp, ritp, EMB, 0);
  // classifier head (overwrites wt scratch + Bpad with log_probs)
  mlp_kernel<<<NN / 4, 256, 0, stream>>>(EMB, mlp_w, mlp_b, out);
}